// Round 2
// baseline (78.321 us; speedup 1.0000x reference)
//
#include <hip/hip_runtime.h>

// CP_Based: out[b,u] = (prod_f rsqrt(1+X^2)) * sum_r prod_f (k0[r,f,u] + X[b,f]*k1[r,f,u])
// X: [B,32] f32, kernel: [2,10,32,8] f32, out: [B,8] f32

typedef float f32x4 __attribute__((ext_vector_type(4)));

#define F 32
#define RANK 10
#define UNITS 8

__global__ __launch_bounds__(256) void cp_based_kernel(
    const float* __restrict__ X,
    const float* __restrict__ K,   // [2,10,32,8] flat
    float* __restrict__ out,
    int B)
{
    int b = blockIdx.x * blockDim.x + threadIdx.x;
    if (b >= B) return;

    // Opaque per-lane zero: forces K addresses onto the vector-memory path
    // (deep vmcnt pipelining, L1-resident 20KB K) instead of scalar s_load
    // streaming through the tiny scalar K$.
    int vzero;
    asm volatile("v_mov_b32 %0, 0" : "=v"(vzero));
    const float* Kv = K + vzero;

    // ---- load X row (8 x float4) and compute pnorm = prod_f rsqrt(1+x^2)
    const f32x4* xrow = reinterpret_cast<const f32x4*>(X + (size_t)b * F);
    float xv[F];
    float pnorm = 1.0f;
#pragma unroll
    for (int i = 0; i < F / 4; ++i) {
        f32x4 v = xrow[i];
#pragma unroll
        for (int j = 0; j < 4; ++j) {
            float x = v[j];
            xv[i * 4 + j] = x;
            pnorm *= __builtin_amdgcn_rsqf(__builtin_fmaf(x, x, 1.0f));
        }
    }

    const int K1_OFF = RANK * F * UNITS;  // offset of the d=1 block (2560 floats)

    f32x4 accA = {0.f, 0.f, 0.f, 0.f};
    f32x4 accB = {0.f, 0.f, 0.f, 0.f};

    for (int r = 0; r < RANK; ++r) {
        f32x4 pA = {1.f, 1.f, 1.f, 1.f};
        f32x4 pB = {1.f, 1.f, 1.f, 1.f};
        const float* k0base = Kv + r * F * UNITS;
        const float* k1base = k0base + K1_OFF;
#pragma unroll
        for (int f = 0; f < F; ++f) {
            f32x4 k0a = *reinterpret_cast<const f32x4*>(k0base + f * UNITS);
            f32x4 k0b = *reinterpret_cast<const f32x4*>(k0base + f * UNITS + 4);
            f32x4 k1a = *reinterpret_cast<const f32x4*>(k1base + f * UNITS);
            f32x4 k1b = *reinterpret_cast<const f32x4*>(k1base + f * UNITS + 4);
            float xf = xv[f];
            f32x4 xs = {xf, xf, xf, xf};
            f32x4 ta = __builtin_elementwise_fma(xs, k1a, k0a);
            f32x4 tb = __builtin_elementwise_fma(xs, k1b, k0b);
            pA *= ta;
            pB *= tb;
        }
        accA += pA;
        accB += pB;
    }

    accA *= pnorm;
    accB *= pnorm;

    float* o = out + (size_t)b * UNITS;
    reinterpret_cast<f32x4*>(o)[0] = accA;
    reinterpret_cast<f32x4*>(o)[1] = accB;
}

extern "C" void kernel_launch(void* const* d_in, const int* in_sizes, int n_in,
                              void* d_out, int out_size, void* d_ws, size_t ws_size,
                              hipStream_t stream) {
    const float* X = (const float*)d_in[0];
    const float* K = (const float*)d_in[1];
    float* out = (float*)d_out;
    int B = in_sizes[0] / F;  // 131072

    dim3 block(256);
    dim3 grid((B + 255) / 256);
    hipLaunchKernelGGL(cp_based_kernel, grid, block, 0, stream, X, K, out, B);
}

// Round 3
// 31.196 us; speedup vs baseline: 2.5106x; 2.5106x over previous
//
#include <hip/hip_runtime.h>

// CP_Based: out[b,u] = (prod_f rsqrt(1+X^2)) * sum_r prod_f (k0[r,f,u] + X[b,f]*k1[r,f,u])
// X: [B,32] f32, kernel: [2,10,32,8] f32, out: [B,8] f32
//
// Parallelization: blockDim=(64,5). Each wave (fixed threadIdx.y) handles a
// rank PAIR {2y, 2y+1} for 64 batch rows -> 5x the waves of the b-only
// mapping (TLP 8/SIMD-class) and 4KB (not 20KB) of scalar-pipe K traffic per
// wave. Rank partials are summed through LDS; wave y==0 applies the norm and
// writes out. K indexing is wave-uniform (readfirstlane-forced) so K rides
// the scalar pipe (s_load) -- VMEM broadcast loads measured 2.8x worse (R2).

typedef float f32x2 __attribute__((ext_vector_type(2)));
typedef float f32x4 __attribute__((ext_vector_type(4)));

#define F 32
#define RANK 10
#define UNITS 8
#define YSPLIT 5

__global__ __launch_bounds__(320) void cp_based_kernel(
    const float* __restrict__ X,
    const float* __restrict__ K,   // [2,10,32,8] flat
    float* __restrict__ out,
    int B)
{
    __shared__ float red[YSPLIT][64][UNITS];   // 10240 B

    const int lane = threadIdx.x;                                   // 0..63
    const int y = __builtin_amdgcn_readfirstlane(threadIdx.y);      // 0..4, forced SGPR
    const int b = blockIdx.x * 64 + lane;

    // ---- load X row (8 x float4)
    const f32x4* xrow = reinterpret_cast<const f32x4*>(X + (size_t)b * F);
    float xv[F];
#pragma unroll
    for (int i = 0; i < F / 4; ++i) {
        f32x4 v = xrow[i];
#pragma unroll
        for (int j = 0; j < 4; ++j) xv[i * 4 + j] = v[j];
    }

    const int K1_OFF = RANK * F * UNITS;   // d=1 block offset (2560 floats)

    f32x2 s0 = {0.f, 0.f}, s1 = {0.f, 0.f}, s2 = {0.f, 0.f}, s3 = {0.f, 0.f};

#pragma unroll
    for (int rr = 0; rr < 2; ++rr) {
        const int r = 2 * y + rr;                         // scalar
        const float* k0b = K + r * F * UNITS;             // scalar base -> s_load
        const float* k1b = k0b + K1_OFF;
        f32x2 p0 = {1.f, 1.f}, p1 = {1.f, 1.f}, p2 = {1.f, 1.f}, p3 = {1.f, 1.f};
#pragma unroll
        for (int f = 0; f < F; ++f) {
            const f32x2* k0 = reinterpret_cast<const f32x2*>(k0b + f * UNITS);
            const f32x2* k1 = reinterpret_cast<const f32x2*>(k1b + f * UNITS);
            float xf = xv[f];
            f32x2 xs = {xf, xf};
            f32x2 t0 = xs * k1[0] + k0[0];
            f32x2 t1 = xs * k1[1] + k0[1];
            f32x2 t2 = xs * k1[2] + k0[2];
            f32x2 t3 = xs * k1[3] + k0[3];
            p0 *= t0;
            p1 *= t1;
            p2 *= t2;
            p3 *= t3;
        }
        s0 += p0; s1 += p1; s2 += p2; s3 += p3;
    }

    // ---- stage rank-pair partials to LDS
    f32x4* redp = reinterpret_cast<f32x4*>(&red[y][lane][0]);
    redp[0] = f32x4{s0[0], s0[1], s1[0], s1[1]};
    redp[1] = f32x4{s2[0], s2[1], s3[0], s3[1]};
    __syncthreads();

    if (y == 0) {
        f32x4 a0 = redp[0];
        f32x4 a1 = redp[1];
#pragma unroll
        for (int k = 1; k < YSPLIT; ++k) {
            const f32x4* q = reinterpret_cast<const f32x4*>(&red[k][lane][0]);
            a0 += q[0];
            a1 += q[1];
        }
        // pnorm = prod_f rsqrt(1+x^2) = rsqrt(prodA) * rsqrt(prodB), split 16/16
        float pA = 1.0f, pB = 1.0f;
#pragma unroll
        for (int f = 0; f < 16; ++f) pA *= __builtin_fmaf(xv[f], xv[f], 1.0f);
#pragma unroll
        for (int f = 16; f < 32; ++f) pB *= __builtin_fmaf(xv[f], xv[f], 1.0f);
        float pn = __builtin_amdgcn_rsqf(pA) * __builtin_amdgcn_rsqf(pB);
        a0 *= pn;
        a1 *= pn;
        f32x4* o = reinterpret_cast<f32x4*>(out + (size_t)b * UNITS);
        o[0] = a0;
        o[1] = a1;
    }
}

extern "C" void kernel_launch(void* const* d_in, const int* in_sizes, int n_in,
                              void* d_out, int out_size, void* d_ws, size_t ws_size,
                              hipStream_t stream) {
    const float* X = (const float*)d_in[0];
    const float* K = (const float*)d_in[1];
    float* out = (float*)d_out;
    int B = in_sizes[0] / F;  // 131072

    dim3 block(64, YSPLIT);
    dim3 grid(B / 64);
    hipLaunchKernelGGL(cp_based_kernel, grid, block, 0, stream, X, K, out, B);
}